// Round 9
// baseline (129.006 us; speedup 1.0000x reference)
//
#include <hip/hip_runtime.h>
#include <hip/hip_bf16.h>
#include <math.h>

#define NB    16384            // batch rows
#define KDIM  2048             // in_dim
#define NCLS  101              // classes
#define NP    10               // npass
#define NTOT  (NP*NCLS)        // 1010
#define NPAD  1024             // padded N for GEMM
#define PM_SIZE (NB*NCLS)
#define CI    (NCLS*KDIM)      // 206848
#define NBLK_PW ((CI + 255) / 256)   // 808 weight blocks; +1 bias block
#define PAD_ELEMS ((NPAD - NTOT) * KDIM)  // 28672
#define NT    64               // K tiles of 32

#define LSQ2PI 0.9189385332046727f
#define HALF_INV_S2SQ 81377.39570642986f   // 0.5*exp(12) = 0.5/sigma2^2

typedef __bf16 bf16x8 __attribute__((ext_vector_type(8)));
typedef float f32x4 __attribute__((ext_vector_type(4)));

__device__ __forceinline__ unsigned short f2bf_bits(float f) {
    union { float f; unsigned u; } v; v.f = f;
    unsigned u = v.u;
    unsigned r = u + 0x7FFFu + ((u >> 16) & 1u);   // RNE
    return (unsigned short)(r >> 16);
}

__device__ __forceinline__ float bfu(unsigned short u) {
    union { unsigned u; float f; } v; v.u = ((unsigned)u) << 16;
    return v.f;
}

__device__ __forceinline__ bf16x8 cvt8(f32x4 a, f32x4 b) {
    bf16x8 r;
    r[0] = (__bf16)a[0]; r[1] = (__bf16)a[1]; r[2] = (__bf16)a[2]; r[3] = (__bf16)a[3];
    r[4] = (__bf16)b[0]; r[5] = (__bf16)b[1]; r[6] = (__bf16)b[2]; r[7] = (__bf16)b[3];
    return r;
}

__device__ __forceinline__ float mix_logprob(float v) {
    float q = v * v;
    float lp1 = -LSQ2PI - 0.5f * q;
    float lp2 = -LSQ2PI + 6.0f - HALF_INV_S2SQ * q;
    return __logf(0.5f * __expf(lp1) + 0.5f * __expf(lp2));
}

// ------- sample w -> bf16 B-matrix + per-block partials; block NBLK_PW does bias -------
__global__ void prep_all(const float* __restrict__ wmu, const float* __restrict__ wrho,
                         const float* __restrict__ eps_w,
                         const float* __restrict__ bmu, const float* __restrict__ brho,
                         const float* __restrict__ eps_b,
                         unsigned short* __restrict__ wB, float* __restrict__ biasN,
                         float* __restrict__ partials) {
    float prior = 0.f, post = 0.f;
    if (blockIdx.x == NBLK_PW) {
        #pragma unroll
        for (int q = 0; q < 4; ++q) {
            const int i = q * 256 + threadIdx.x;     // 0..1023
            float bv = 0.f;
            if (i < NTOT) {
                const int c = i % NCLS;
                const float sigma = log1pf(__expf(brho[c]));
                const float eps = eps_b[i];
                bv = fmaf(sigma, eps, bmu[c]);
                prior += mix_logprob(bv);
                post += -LSQ2PI - __logf(sigma) - 0.5f * eps * eps;
            }
            biasN[i] = bv;
        }
    } else {
        const int t = blockIdx.x * 256 + threadIdx.x;
        if (t < PAD_ELEMS) wB[(size_t)NTOT * KDIM + t] = 0;   // zero pad rows
        if (t < CI) {
            const float mu = wmu[t];
            const float sigma = log1pf(__expf(wrho[t]));
            const float nls = -__logf(sigma);
            const int c = t / KDIM, i = t & (KDIM - 1);
            #pragma unroll
            for (int n = 0; n < NP; ++n) {
                const float eps = eps_w[(size_t)n * CI + t];
                const float w = fmaf(sigma, eps, mu);
                wB[(size_t)(n * NCLS + c) * KDIM + i] = f2bf_bits(w);
                prior += mix_logprob(w);
                post += nls - LSQ2PI - 0.5f * eps * eps;
            }
        }
    }
    for (int off = 32; off; off >>= 1) {
        prior += __shfl_xor(prior, off);
        post  += __shfl_xor(post, off);
    }
    __shared__ float sp[4], so[4];
    const int wid = threadIdx.x >> 6;
    if ((threadIdx.x & 63) == 0) { sp[wid] = prior; so[wid] = post; }
    __syncthreads();
    if (threadIdx.x == 0) {
        partials[blockIdx.x * 2]     = sp[0] + sp[1] + sp[2] + sp[3];
        partials[blockIdx.x * 2 + 1] = so[0] + so[1] + so[2] + so[3];
    }
}

// ====== 256x256 BK=32 2-phase bf16 MFMA GEMM, A staged as f32 straight from x ======
// 512 threads (8 waves 2M x 4N, per-wave 128x64). LDS 96 KiB:
//   A f32 [buf][half][128 rows][32 f32] 4 x 16 KB @0; B bf16 [buf][256 rows][32] 2 x 16 KB @65536.
// Tile t (buf = t&1):
//   P1: LDA(0..7) (16 ds_read_b128 f32 + cvt) + LDB(0..3) (4 reads); SBAR; 16 MFMA; SBAR
//   P2: stage A(t+2)+B(t+2) into buf (6 global_load_lds; all buf reads finished in P1,
//       barrier-separated); 16 MFMA (operands already in regs -> no lgkm stall);
//       vmcnt(6) (drains t+1's 6 gloads, issued a full tile ago; keeps t+2's); barrier.
// Swizzle: A rows = 8 16B-slots, slot^(row&7) both sides; B rows = 4 slots, slot^(row&3)
// both sides (4-way conflict on the 4 B-reads -- accepted, 20% of LDS traffic).
__device__ __forceinline__ void stage_A_half(const float* __restrict__ X,
                                             int grow0, int k0, int lds_byte_base,
                                             int tid, char* ldsp) {
    #pragma unroll
    for (int l = 0; l < 2; ++l) {
        const int flat = l * 512 + tid;            // 16B slot 0..1023 (128 rows x 8)
        const int row = flat >> 3, j = flat & 7;
        const int jsw = j ^ (row & 7);
        const float* src = X + (size_t)(grow0 + row) * KDIM + k0 + jsw * 4;
        __builtin_amdgcn_global_load_lds(
            (const __attribute__((address_space(1))) void*)src,
            (__attribute__((address_space(3))) void*)(ldsp + lds_byte_base + flat * 16),
            16, 0, 0);
    }
}

__device__ __forceinline__ void stage_B32(const unsigned short* __restrict__ Bm,
                                          int grow0, int k0, int lds_byte_base,
                                          int tid, char* ldsp) {
    #pragma unroll
    for (int l = 0; l < 2; ++l) {
        const int flat = l * 512 + tid;            // 16B slot 0..1023 (256 rows x 4)
        const int row = flat >> 2, j = flat & 3;
        const int jsw = j ^ (row & 3);
        const unsigned short* src = Bm + (size_t)(grow0 + row) * KDIM + k0 + jsw * 8;
        __builtin_amdgcn_global_load_lds(
            (const __attribute__((address_space(1))) void*)src,
            (__attribute__((address_space(3))) void*)(ldsp + lds_byte_base + flat * 16),
            16, 0, 0);
    }
}

#define STAGE_A(buf, half, tt) stage_A_half(X, bm + (half) * 128, (tt) * 32, ((buf) * 2 + (half)) * 16384, tid, ldsp)
#define STAGE_B(buf, tt)       stage_B32(Bm, bn, (tt) * 32, 65536 + (buf) * 16384, tid, ldsp)

#define LDA(mf, buf) do { \
    const int lr_ = (mf) * 16 + l15;                  /* local row in wave's half */ \
    const char* p_ = ldsp + ((buf) * 2 + wr) * 16384 + lr_ * 128; \
    const int sw_ = lr_ & 7; \
    f32x4 lo_ = *(const f32x4*)(p_ + ((((l4 << 1)    ) ^ sw_) << 4)); \
    f32x4 hi_ = *(const f32x4*)(p_ + ((((l4 << 1) + 1) ^ sw_) << 4)); \
    af[mf] = cvt8(lo_, hi_); \
} while (0)

#define LDB(nf, buf) do { \
    const int rb_ = wc * 64 + (nf) * 16 + l15; \
    bf[nf] = *(const bf16x8*)(ldsp + 65536 + (buf) * 16384 + rb_ * 64 + ((l4 ^ (rb_ & 3)) << 4)); \
} while (0)

#define MM(mh, nh) do { \
    __builtin_amdgcn_s_setprio(1); \
    _Pragma("unroll") \
    for (int mi = 0; mi < 4; ++mi) \
        _Pragma("unroll") \
        for (int ni = 0; ni < 2; ++ni) \
            acc[(mh) * 4 + mi][(nh) * 2 + ni] = __builtin_amdgcn_mfma_f32_16x16x32_bf16( \
                af[(mh) * 4 + mi], bf[(nh) * 2 + ni], acc[(mh) * 4 + mi][(nh) * 2 + ni], 0, 0, 0); \
    __builtin_amdgcn_s_setprio(0); \
} while (0)

#define SBAR() do { \
    __builtin_amdgcn_sched_barrier(0); \
    __builtin_amdgcn_s_barrier(); \
    __builtin_amdgcn_sched_barrier(0); \
} while (0)

#define TILE(t, buf) do { \
    /* P1: all ds_reads of tile t */ \
    LDA(0, buf); LDA(1, buf); LDA(2, buf); LDA(3, buf); \
    LDA(4, buf); LDA(5, buf); LDA(6, buf); LDA(7, buf); \
    LDB(0, buf); LDB(1, buf); LDB(2, buf); LDB(3, buf); \
    SBAR(); \
    MM(0, 0); MM(0, 1); \
    SBAR(); \
    /* P2: stage t+2 into buf (reads of buf all done, barrier-separated); read-free MFMAs */ \
    if ((t) + 2 < NT) { STAGE_A(buf, 0, (t) + 2); STAGE_A(buf, 1, (t) + 2); STAGE_B(buf, (t) + 2); } \
    __builtin_amdgcn_sched_barrier(0); \
    MM(1, 1); MM(1, 0); \
    __builtin_amdgcn_sched_barrier(0); \
    if ((t) + 2 < NT)      { asm volatile("s_waitcnt vmcnt(6)"); __builtin_amdgcn_s_barrier(); } \
    else if ((t) + 1 < NT) { asm volatile("s_waitcnt vmcnt(0)"); __builtin_amdgcn_s_barrier(); } \
    __builtin_amdgcn_sched_barrier(0); \
} while (0)

__global__ void __launch_bounds__(512, 2) gemm8f(
    const float* __restrict__ X,             // [NB, KDIM] f32
    const unsigned short* __restrict__ Bm,   // [NPAD, KDIM] bf16 bits
    const float* __restrict__ biasN,
    unsigned short* __restrict__ Co)         // [NB, NPAD] bf16 bits
{
    __shared__ __align__(16) char ldsp[98304];   // 96 KiB
    const int tid = threadIdx.x;
    const int lane = tid & 63, wid = tid >> 6;
    const int wr = wid >> 2, wc = wid & 3;               // 2M x 4N waves
    const int l15 = lane & 15, l4 = lane >> 4;

    const int b = blockIdx.x;
    const int wg = (b & 7) * 32 + (b >> 3);              // bijective XCD swizzle, 256 blocks
    const int bm = (wg >> 2) * 256;
    const int bn = (wg & 3) * 256;

    f32x4 acc[8][4] = {{}};
    bf16x8 af[8], bf[4];

    // ---- prologue: stage tile0 (buf0) + tile1 (buf1); wait tile0; barrier
    STAGE_A(0, 0, 0); STAGE_A(0, 1, 0); STAGE_B(0, 0);
    STAGE_A(1, 0, 1); STAGE_A(1, 1, 1); STAGE_B(1, 1);
    __builtin_amdgcn_sched_barrier(0);
    asm volatile("s_waitcnt vmcnt(6)");
    __builtin_amdgcn_s_barrier();
    __builtin_amdgcn_sched_barrier(0);

    #pragma unroll 1
    for (int tt = 0; tt < NT / 2; ++tt) {
        const int t0 = 2 * tt;
        TILE(t0, 0);
        TILE(t0 + 1, 1);
    }

    // ---- epilogue: bias + bf16 store (C frag: col=lane&15, row=(lane>>4)*4+r)
    #pragma unroll
    for (int n = 0; n < 4; ++n) {
        const int col = bn + wc * 64 + n * 16 + l15;
        const float bv = biasN[col];
        #pragma unroll
        for (int m = 0; m < 8; ++m) {
            const int row0 = bm + wr * 128 + m * 16 + l4 * 4;
            #pragma unroll
            for (int r = 0; r < 4; ++r)
                Co[(size_t)(row0 + r) * NPAD + col] = f2bf_bits(acc[m][n][r] + bv);
        }
    }
}

// ---------------- softmax stats (bf16 logits): one wave per batch row ----------------
__global__ void stats_kernel(const unsigned short* __restrict__ Co,
                             const float* __restrict__ partials,
                             float* __restrict__ out) {
    const int lane = threadIdx.x & 63;
    const int wid = threadIdx.x >> 6;
    const int b = blockIdx.x * 4 + wid;
    const unsigned short* row = Co + (size_t)b * NPAD;
    float* pm = out;
    float* aleat_out = out + PM_SIZE + 2;
    float* epi_out   = out + PM_SIZE + 2 + NB;

    const bool has2 = lane < (NCLS - 64);
    float p1s[NP], p2s[NP];
    float pm1 = 0.f, pm2 = 0.f, pb1 = 0.f, pb2 = 0.f, sqacc = 0.f;

    for (int n = 0; n < NP; ++n) {
        const float v1 = bfu(row[n * NCLS + lane]);
        const float v2 = has2 ? bfu(row[n * NCLS + 64 + lane]) : 0.f;
        const float e1 = __expf(v1 - 20.f);
        const float e2 = has2 ? __expf(v2 - 20.f) : 0.f;
        float s = e1 + e2;
        for (int off = 32; off; off >>= 1) s += __shfl_xor(s, off);
        const float rs = 1.0f / s;
        const float p1 = e1 * rs, p2 = e2 * rs;
        sqacc += p1 * p1 + p2 * p2;
        pm1 += v1; pm2 += v2;
        pb1 += p1; pb2 += p2;
        p1s[n] = p1; p2s[n] = p2;
    }
    const float inv_n = 1.0f / NP;
    pb1 *= inv_n; pb2 *= inv_n;
    pm[(size_t)b * NCLS + lane] = pm1 * inv_n;
    if (has2) pm[(size_t)b * NCLS + 64 + lane] = pm2 * inv_n;
    float epi = 0.f;
    #pragma unroll
    for (int n = 0; n < NP; ++n) {
        const float d1 = p1s[n] - pb1;
        const float d2 = p2s[n] - pb2;
        epi += d1 * d1 + d2 * d2;
    }
    for (int off = 32; off; off >>= 1) {
        epi   += __shfl_xor(epi, off);
        sqacc += __shfl_xor(sqacc, off);
    }
    if (lane == 0) {
        aleat_out[b] = 1.0f - sqacc * inv_n;
        epi_out[b]   = epi * inv_n;
    }
    // block 0, wave 0: reduce prior/posterior partials -> scalars
    if (blockIdx.x == 0 && wid == 0) {
        float a = 0.f, c = 0.f;
        for (int i = lane; i < NBLK_PW + 1; i += 64) {
            a += partials[2 * i];
            c += partials[2 * i + 1];
        }
        for (int off = 32; off; off >>= 1) {
            a += __shfl_xor(a, off);
            c += __shfl_xor(c, off);
        }
        if (lane == 0) {
            out[PM_SIZE]     = a * (1.0f / NP);
            out[PM_SIZE + 1] = c * (1.0f / NP);
        }
    }
}

extern "C" void kernel_launch(void* const* d_in, const int* in_sizes, int n_in,
                              void* d_out, int out_size, void* d_ws, size_t ws_size,
                              hipStream_t stream) {
    const float* x     = (const float*)d_in[0];
    const float* wmu   = (const float*)d_in[1];
    const float* wrho  = (const float*)d_in[2];
    const float* bmu   = (const float*)d_in[3];
    const float* brho  = (const float*)d_in[4];
    const float* eps_w = (const float*)d_in[5];
    const float* eps_b = (const float*)d_in[6];
    float* out = (float*)d_out;

    char* ws = (char*)d_ws;
    const size_t OFF_WB    = 0;                          // 1024*2048*2  = 4194304
    const size_t OFF_COUT  = OFF_WB + 4194304;           // 16384*1024*2 = 33554432
    const size_t OFF_BIASN = OFF_COUT + 33554432;        // 4096
    const size_t OFF_PART  = OFF_BIASN + 4096;           // 809*2*4

    unsigned short* wB   = (unsigned short*)(ws + OFF_WB);
    unsigned short* Co   = (unsigned short*)(ws + OFF_COUT);
    float* biasN    = (float*)(ws + OFF_BIASN);
    float* partials = (float*)(ws + OFF_PART);

    prep_all<<<NBLK_PW + 1, 256, 0, stream>>>(wmu, wrho, eps_w, bmu, brho, eps_b,
                                              wB, biasN, partials);
    gemm8f<<<256, 512, 0, stream>>>(x, wB, biasN, Co);
    stats_kernel<<<NB / 4, 256, 0, stream>>>(Co, partials, out);
}

// Round 10
// 125.429 us; speedup vs baseline: 1.0285x; 1.0285x over previous
//
#include <hip/hip_runtime.h>
#include <hip/hip_bf16.h>
#include <math.h>

#define NB    16384            // batch rows
#define KDIM  2048             // in_dim
#define NCLS  101              // classes
#define NP    10               // npass
#define NTOT  (NP*NCLS)        // 1010
#define NPAD  1024             // padded N for GEMM
#define PM_SIZE (NB*NCLS)
#define CI    (NCLS*KDIM)      // 206848
#define NBLK_CVT 16384         // cvt blocks
#define NBLK_PW ((CI + 255) / 256)   // 808 weight blocks; +1 bias block
#define PAD_ELEMS ((NPAD - NTOT) * KDIM)  // 28672

#define LSQ2PI 0.9189385332046727f
#define HALF_INV_S2SQ 81377.39570642986f   // 0.5*exp(12) = 0.5/sigma2^2

typedef __bf16 bf16x8 __attribute__((ext_vector_type(8)));
typedef float f32x4 __attribute__((ext_vector_type(4)));
typedef unsigned short u16x8 __attribute__((ext_vector_type(8)));

__device__ __forceinline__ unsigned short f2bf_bits(float f) {
    union { float f; unsigned u; } v; v.f = f;
    unsigned u = v.u;
    unsigned r = u + 0x7FFFu + ((u >> 16) & 1u);   // RNE
    return (unsigned short)(r >> 16);
}

__device__ __forceinline__ float bfu(unsigned short u) {
    union { unsigned u; float f; } v; v.u = ((unsigned)u) << 16;
    return v.f;
}

__device__ __forceinline__ float mix_logprob(float v) {
    float q = v * v;
    float lp1 = -LSQ2PI - 0.5f * q;
    float lp2 = -LSQ2PI + 6.0f - HALF_INV_S2SQ * q;
    return __logf(0.5f * __expf(lp1) + 0.5f * __expf(lp2));
}

// ------- fused: x->bf16 cvt blocks + weight-sampling blocks + bias block -------
__global__ void prep_all(const float* __restrict__ x, unsigned short* __restrict__ xb,
                         const float* __restrict__ wmu, const float* __restrict__ wrho,
                         const float* __restrict__ eps_w,
                         const float* __restrict__ bmu, const float* __restrict__ brho,
                         const float* __restrict__ eps_b,
                         unsigned short* __restrict__ wB, float* __restrict__ biasN,
                         float* __restrict__ partials) {
    if (blockIdx.x < NBLK_CVT) {
        const int t = blockIdx.x * 256 + threadIdx.x;
        const float4* x4 = (const float4*)x;
        float4 a = x4[2 * t];
        float4 b = x4[2 * t + 1];
        u16x8 o;
        o[0] = f2bf_bits(a.x); o[1] = f2bf_bits(a.y); o[2] = f2bf_bits(a.z); o[3] = f2bf_bits(a.w);
        o[4] = f2bf_bits(b.x); o[5] = f2bf_bits(b.y); o[6] = f2bf_bits(b.z); o[7] = f2bf_bits(b.w);
        *(u16x8*)(xb + 8 * (size_t)t) = o;
        return;
    }
    const int pb = blockIdx.x - NBLK_CVT;       // 0..NBLK_PW
    float prior = 0.f, post = 0.f;
    if (pb == NBLK_PW) {
        #pragma unroll
        for (int q = 0; q < 4; ++q) {
            const int i = q * 256 + threadIdx.x;     // 0..1023
            float bv = 0.f;
            if (i < NTOT) {
                const int c = i % NCLS;
                const float sigma = log1pf(__expf(brho[c]));
                const float eps = eps_b[i];
                bv = fmaf(sigma, eps, bmu[c]);
                prior += mix_logprob(bv);
                post += -LSQ2PI - __logf(sigma) - 0.5f * eps * eps;
            }
            biasN[i] = bv;
        }
    } else {
        const int t = pb * 256 + threadIdx.x;
        if (t < PAD_ELEMS) wB[(size_t)NTOT * KDIM + t] = 0;   // zero pad rows
        if (t < CI) {
            const float mu = wmu[t];
            const float sigma = log1pf(__expf(wrho[t]));
            const float nls = -__logf(sigma);
            const int c = t / KDIM, i = t & (KDIM - 1);
            #pragma unroll
            for (int n = 0; n < NP; ++n) {
                const float eps = eps_w[(size_t)n * CI + t];
                const float w = fmaf(sigma, eps, mu);
                wB[(size_t)(n * NCLS + c) * KDIM + i] = f2bf_bits(w);
                prior += mix_logprob(w);
                post += nls - LSQ2PI - 0.5f * eps * eps;
            }
        }
    }
    for (int off = 32; off; off >>= 1) {
        prior += __shfl_xor(prior, off);
        post  += __shfl_xor(post, off);
    }
    __shared__ float sp[4], so[4];
    const int wid = threadIdx.x >> 6;
    if ((threadIdx.x & 63) == 0) { sp[wid] = prior; so[wid] = post; }
    __syncthreads();
    if (threadIdx.x == 0) {
        partials[pb * 2]     = sp[0] + sp[1] + sp[2] + sp[3];
        partials[pb * 2 + 1] = so[0] + so[1] + so[2] + so[3];
    }
}

// =============== 256x256 8-phase bf16 MFMA GEMM (R6/R8 schedule, coalesced epilogue) ===============
__device__ __forceinline__ void stage_half(const unsigned short* __restrict__ G,
                                           int grow0, int k0, int lds_byte_base,
                                           int tid, char* ldsp) {
    #pragma unroll
    for (int l = 0; l < 2; ++l) {
        const int flat = l * 512 + tid;            // 16B slot index 0..1023
        const int row = flat >> 3, j = flat & 7;
        const int jsw = j ^ (row & 7);
        const unsigned short* src = G + (size_t)(grow0 + row) * KDIM + k0 + jsw * 8;
        __builtin_amdgcn_global_load_lds(
            (const __attribute__((address_space(1))) void*)src,
            (__attribute__((address_space(3))) void*)(ldsp + lds_byte_base + flat * 16),
            16, 0, 0);
    }
}

#define STAGE_A(buf, half, tt) stage_half(A,  bm + (half) * 128, (tt) * 64, ((buf) * 4 + (half)) * 16384, tid, ldsp)
#define STAGE_B(buf, half, tt) stage_half(Bm, bn + (half) * 128, (tt) * 64, ((buf) * 4 + 2 + (half)) * 16384, tid, ldsp)

#define LDA(mf, buf) do { \
    const int rowh_ = (mf) * 16 + l15; \
    const char* p_ = ldsp + ((buf) * 4 + aregion) * 16384 + rowh_ * 128; \
    const int sw_ = (rowh_ & 7) << 4; \
    af[(mf) & 3][0] = *(const bf16x8*)(p_ + ((l4 << 4) ^ sw_)); \
    af[(mf) & 3][1] = *(const bf16x8*)(p_ + (((4 + l4) << 4) ^ sw_)); \
} while (0)

#define LDB(nf, buf) do { \
    const int rowh_ = (wc & 1) * 64 + (nf) * 16 + l15; \
    const char* p_ = ldsp + ((buf) * 4 + bregion) * 16384 + rowh_ * 128; \
    const int sw_ = (rowh_ & 7) << 4; \
    bf[nf][0] = *(const bf16x8*)(p_ + ((l4 << 4) ^ sw_)); \
    bf[nf][1] = *(const bf16x8*)(p_ + (((4 + l4) << 4) ^ sw_)); \
} while (0)

#define MM(mh, nh) do { \
    __builtin_amdgcn_s_setprio(1); \
    _Pragma("unroll") \
    for (int mi = 0; mi < 4; ++mi) \
        _Pragma("unroll") \
        for (int ni = 0; ni < 2; ++ni) \
            _Pragma("unroll") \
            for (int kk = 0; kk < 2; ++kk) \
                acc[(mh) * 4 + mi][(nh) * 2 + ni] = __builtin_amdgcn_mfma_f32_16x16x32_bf16( \
                    af[mi][kk], bf[(nh) * 2 + ni][kk], acc[(mh) * 4 + mi][(nh) * 2 + ni], 0, 0, 0); \
    __builtin_amdgcn_s_setprio(0); \
} while (0)

#define SBAR() do { \
    __builtin_amdgcn_sched_barrier(0); \
    __builtin_amdgcn_s_barrier(); \
    __builtin_amdgcn_sched_barrier(0); \
} while (0)

__global__ void __launch_bounds__(512, 2) gemm8(
    const unsigned short* __restrict__ A,    // [NB, KDIM] bf16 bits
    const unsigned short* __restrict__ Bm,   // [NPAD, KDIM] bf16 bits
    const float* __restrict__ biasN,
    unsigned short* __restrict__ Co)         // [NB, NPAD] bf16 bits
{
    __shared__ __align__(16) unsigned short lds[65536];   // 128 KiB
    char* ldsp = (char*)lds;
    const int tid = threadIdx.x;
    const int lane = tid & 63, wid = tid >> 6;
    const int wr = wid >> 2, wc = wid & 3;               // 2M x 4N waves
    const int l15 = lane & 15, l4 = lane >> 4;

    const int b = blockIdx.x;
    const int wg = (b & 7) * 32 + (b >> 3);              // bijective XCD swizzle, 256 blocks
    const int bm = (wg >> 2) * 256;
    const int bn = (wg & 3) * 256;

    const int aregion = wr;
    const int bregion = 2 + (wc >> 1);

    f32x4 acc[8][4] = {{}};
    bf16x8 af[4][2], bf[4][2];

    // ---- prologue: tile0 fully + tile1 {A0,B0,B1}; A1(1) staged at P1(t=0)
    STAGE_A(0, 0, 0); STAGE_A(0, 1, 0); STAGE_B(0, 0, 0); STAGE_B(0, 1, 0);
    STAGE_A(1, 0, 1); STAGE_B(1, 0, 1); STAGE_B(1, 1, 1);
    __builtin_amdgcn_sched_barrier(0);
    asm volatile("s_waitcnt vmcnt(6)");
    SBAR();

    for (int t = 0; t < 32; ++t) {
        const int buf = t & 1, nbuf = buf ^ 1;
        // --- P1: read A(mh0)+B(nh0) of t; stage A1(t+1); lgkm drain hint (12 reads)
        LDA(0, buf); LDA(1, buf); LDA(2, buf); LDA(3, buf);
        LDB(0, buf); LDB(1, buf);
        if (t + 1 < 32) STAGE_A(nbuf, 1, t + 1);
        __builtin_amdgcn_sched_barrier(0);
        asm volatile("s_waitcnt lgkmcnt(8)");
        SBAR();
        MM(0, 0);
        SBAR();
        // --- P2: read B(nh1)
        LDB(2, buf); LDB(3, buf);
        SBAR();
        MM(0, 1);
        SBAR();
        // --- P3: read A(mh1); stage B0(t+2)
        LDA(4, buf); LDA(5, buf); LDA(6, buf); LDA(7, buf);
        if (t + 2 < 32) STAGE_B(buf, 0, t + 2);
        SBAR();
        MM(1, 1);
        SBAR();
        // --- P4: no reads; stage A0(t+2), B1(t+2); counted vmcnt gate
        if (t + 2 < 32) { STAGE_A(buf, 0, t + 2); STAGE_B(buf, 1, t + 2); }
        SBAR();
        MM(1, 0);
        __builtin_amdgcn_sched_barrier(0);
        if (t < 30) { asm volatile("s_waitcnt vmcnt(6)"); }
        else        { asm volatile("s_waitcnt vmcnt(0)"); }
        __builtin_amdgcn_sched_barrier(0);
        __builtin_amdgcn_s_barrier();
        __builtin_amdgcn_sched_barrier(0);
    }

    // ---- epilogue E1: acc(+bias)->bf16 into LDS [256 rows][32 slots of 16B],
    //      slot XOR (row&31) so E2's column-of-slots read is conflict-free.
    #pragma unroll
    for (int n = 0; n < 4; ++n) {
        const int col = wc * 64 + n * 16 + l15;          // local col 0..255
        const float bv = biasN[bn + col];
        #pragma unroll
        for (int m = 0; m < 8; ++m) {
            const int row0 = wr * 128 + m * 16 + l4 * 4; // local row
            #pragma unroll
            for (int r = 0; r < 4; ++r) {
                const int row = row0 + r;
                const int slot = (col >> 3) ^ (row & 31);
                *(unsigned short*)(ldsp + row * 512 + slot * 16 + (col & 7) * 2)
                    = f2bf_bits(acc[m][n][r] + bv);
            }
        }
    }
    SBAR();
    // ---- epilogue E2: stream 256B contiguous per thread to global (full-line writes)
    {
        const int grow = tid >> 1, gpart = tid & 1;
        unsigned short* dst = Co + (size_t)(bm + grow) * NPAD + bn + gpart * 128;
        const char* srcrow = ldsp + grow * 512;
        #pragma unroll
        for (int q = 0; q < 16; ++q) {
            const int slot = (gpart * 16 + q) ^ (grow & 31);
            *(u16x8*)(dst + q * 8) = *(const u16x8*)(srcrow + slot * 16);
        }
    }
}

// ---------------- softmax stats (bf16 logits): one wave per batch row ----------------
// No max-reduce: fixed shift exp(v-20). No sum(p)-reduce (==1). One cross-lane pass.
__global__ void stats_kernel(const unsigned short* __restrict__ Co,
                             const float* __restrict__ partials,
                             float* __restrict__ out) {
    const int lane = threadIdx.x & 63;
    const int wid = threadIdx.x >> 6;
    const int b = blockIdx.x * 4 + wid;
    const unsigned short* row = Co + (size_t)b * NPAD;
    float* pm = out;
    float* aleat_out = out + PM_SIZE + 2;
    float* epi_out   = out + PM_SIZE + 2 + NB;

    const bool has2 = lane < (NCLS - 64);
    float p1s[NP], p2s[NP];
    float pm1 = 0.f, pm2 = 0.f, pb1 = 0.f, pb2 = 0.f, sqacc = 0.f;

    for (int n = 0; n < NP; ++n) {
        const float v1 = bfu(row[n * NCLS + lane]);
        const float v2 = has2 ? bfu(row[n * NCLS + 64 + lane]) : 0.f;
        const float e1 = __expf(v1 - 20.f);
        const float e2 = has2 ? __expf(v2 - 20.f) : 0.f;
        float s = e1 + e2;
        for (int off = 32; off; off >>= 1) s += __shfl_xor(s, off);
        const float rs = 1.0f / s;
        const float p1 = e1 * rs, p2 = e2 * rs;
        sqacc += p1 * p1 + p2 * p2;
        pm1 += v1; pm2 += v2;
        pb1 += p1; pb2 += p2;
        p1s[n] = p1; p2s[n] = p2;
    }
    const float inv_n = 1.0f / NP;
    pb1 *= inv_n; pb2 *= inv_n;
    pm[(size_t)b * NCLS + lane] = pm1 * inv_n;
    if (has2) pm[(size_t)b * NCLS + 64 + lane] = pm2 * inv_n;
    float epi = 0.f;
    #pragma unroll
    for (int n = 0; n < NP; ++n) {
        const float d1 = p1s[n] - pb1;
        const float d2 = p2s[n] - pb2;
        epi += d1 * d1 + d2 * d2;
    }
    for (int off = 32; off; off >>= 1) {
        epi   += __shfl_xor(epi, off);
        sqacc += __shfl_xor(sqacc, off);
    }
    if (lane == 0) {
        aleat_out[b] = 1.0f - sqacc * inv_n;
        epi_out[b]   = epi * inv_n;
    }
    // block 0, wave 0: reduce prior/posterior partials -> scalars
    if (blockIdx.x == 0 && wid == 0) {
        float a = 0.f, c = 0.f;
        for (int i = lane; i < NBLK_PW + 1; i += 64) {
            a += partials[2 * i];
            c += partials[2 * i + 1];
        }
        for (int off = 32; off; off >>= 1) {
            a += __shfl_xor(a, off);
            c += __shfl_xor(c, off);
        }
        if (lane == 0) {
            out[PM_SIZE]     = a * (1.0f / NP);
            out[PM_SIZE + 1] = c * (1.0f / NP);
        }
    }
}

extern "C" void kernel_launch(void* const* d_in, const int* in_sizes, int n_in,
                              void* d_out, int out_size, void* d_ws, size_t ws_size,
                              hipStream_t stream) {
    const float* x     = (const float*)d_in[0];
    const float* wmu   = (const float*)d_in[1];
    const float* wrho  = (const float*)d_in[2];
    const float* bmu   = (const float*)d_in[3];
    const float* brho  = (const float*)d_in[4];
    const float* eps_w = (const float*)d_in[5];
    const float* eps_b = (const float*)d_in[6];
    float* out = (float*)d_out;

    char* ws = (char*)d_ws;
    const size_t OFF_XB    = 0;                          // 16384*2048*2 = 67108864
    const size_t OFF_WB    = 67108864;                   // 1024*2048*2  =  4194304
    const size_t OFF_COUT  = OFF_WB + 4194304;           // 16384*1024*2 = 33554432
    const size_t OFF_BIASN = OFF_COUT + 33554432;        // 4096
    const size_t OFF_PART  = OFF_BIASN + 4096;           // 809*2*4

    unsigned short* xb   = (unsigned short*)(ws + OFF_XB);
    unsigned short* wB   = (unsigned short*)(ws + OFF_WB);
    unsigned short* Co   = (unsigned short*)(ws + OFF_COUT);
    float* biasN    = (float*)(ws + OFF_BIASN);
    float* partials = (float*)(ws + OFF_PART);

    prep_all<<<NBLK_CVT + NBLK_PW + 1, 256, 0, stream>>>(x, xb, wmu, wrho, eps_w,
                                                         bmu, brho, eps_b,
                                                         wB, biasN, partials);
    gemm8<<<256, 512, 0, stream>>>(xb, wB, biasN, Co);
    stats_kernel<<<NB / 4, 256, 0, stream>>>(Co, partials, out);
}

// Round 11
// 121.179 us; speedup vs baseline: 1.0646x; 1.0351x over previous
//
#include <hip/hip_runtime.h>
#include <hip/hip_bf16.h>
#include <math.h>

#define NB    16384            // batch rows
#define KDIM  2048             // in_dim
#define NCLS  101              // classes
#define NP    10               // npass
#define NTOT  (NP*NCLS)        // 1010
#define NPAD  1024             // padded N for GEMM
#define PM_SIZE (NB*NCLS)
#define CI    (NCLS*KDIM)      // 206848
#define NBLK_CVT 16384         // cvt blocks
#define NBLK_PW ((CI + 255) / 256)   // 808 weight blocks; +1 bias block
#define PAD_ELEMS ((NPAD - NTOT) * KDIM)  // 28672

#define LSQ2PI 0.9189385332046727f
#define HALF_INV_S2SQ 81377.39570642986f   // 0.5*exp(12) = 0.5/sigma2^2

typedef __bf16 bf16x8 __attribute__((ext_vector_type(8)));
typedef float f32x4 __attribute__((ext_vector_type(4)));
typedef unsigned short u16x8 __attribute__((ext_vector_type(8)));

__device__ __forceinline__ unsigned short f2bf_bits(float f) {
    union { float f; unsigned u; } v; v.f = f;
    unsigned u = v.u;
    unsigned r = u + 0x7FFFu + ((u >> 16) & 1u);   // RNE
    return (unsigned short)(r >> 16);
}

__device__ __forceinline__ float bfu(unsigned short u) {
    union { unsigned u; float f; } v; v.u = ((unsigned)u) << 16;
    return v.f;
}

__device__ __forceinline__ float mix_logprob(float v) {
    float q = v * v;
    float lp1 = -LSQ2PI - 0.5f * q;
    float lp2 = -LSQ2PI + 6.0f - HALF_INV_S2SQ * q;
    return __logf(0.5f * __expf(lp1) + 0.5f * __expf(lp2));
}

// ------- fused: x->bf16 cvt blocks + weight-sampling blocks + bias block -------
__global__ void prep_all(const float* __restrict__ x, unsigned short* __restrict__ xb,
                         const float* __restrict__ wmu, const float* __restrict__ wrho,
                         const float* __restrict__ eps_w,
                         const float* __restrict__ bmu, const float* __restrict__ brho,
                         const float* __restrict__ eps_b,
                         unsigned short* __restrict__ wB, float* __restrict__ biasN,
                         float* __restrict__ partials) {
    if (blockIdx.x < NBLK_CVT) {
        const int t = blockIdx.x * 256 + threadIdx.x;
        const float4* x4 = (const float4*)x;
        float4 a = x4[2 * t];
        float4 b = x4[2 * t + 1];
        u16x8 o;
        o[0] = f2bf_bits(a.x); o[1] = f2bf_bits(a.y); o[2] = f2bf_bits(a.z); o[3] = f2bf_bits(a.w);
        o[4] = f2bf_bits(b.x); o[5] = f2bf_bits(b.y); o[6] = f2bf_bits(b.z); o[7] = f2bf_bits(b.w);
        *(u16x8*)(xb + 8 * (size_t)t) = o;
        return;
    }
    const int pb = blockIdx.x - NBLK_CVT;       // 0..NBLK_PW
    float prior = 0.f, post = 0.f;
    if (pb == NBLK_PW) {
        #pragma unroll
        for (int q = 0; q < 4; ++q) {
            const int i = q * 256 + threadIdx.x;     // 0..1023
            float bv = 0.f;
            if (i < NTOT) {
                const int c = i % NCLS;
                const float sigma = log1pf(__expf(brho[c]));
                const float eps = eps_b[i];
                bv = fmaf(sigma, eps, bmu[c]);
                prior += mix_logprob(bv);
                post += -LSQ2PI - __logf(sigma) - 0.5f * eps * eps;
            }
            biasN[i] = bv;
        }
    } else {
        const int t = pb * 256 + threadIdx.x;
        if (t < PAD_ELEMS) wB[(size_t)NTOT * KDIM + t] = 0;   // zero pad rows
        if (t < CI) {
            const float mu = wmu[t];
            const float sigma = log1pf(__expf(wrho[t]));
            const float nls = -__logf(sigma);
            const int c = t / KDIM, i = t & (KDIM - 1);
            #pragma unroll
            for (int n = 0; n < NP; ++n) {
                const float eps = eps_w[(size_t)n * CI + t];
                const float w = fmaf(sigma, eps, mu);
                wB[(size_t)(n * NCLS + c) * KDIM + i] = f2bf_bits(w);
                prior += mix_logprob(w);
                post += nls - LSQ2PI - 0.5f * eps * eps;
            }
        }
    }
    for (int off = 32; off; off >>= 1) {
        prior += __shfl_xor(prior, off);
        post  += __shfl_xor(post, off);
    }
    __shared__ float sp[4], so[4];
    const int wid = threadIdx.x >> 6;
    if ((threadIdx.x & 63) == 0) { sp[wid] = prior; so[wid] = post; }
    __syncthreads();
    if (threadIdx.x == 0) {
        partials[pb * 2]     = sp[0] + sp[1] + sp[2] + sp[3];
        partials[pb * 2 + 1] = so[0] + so[1] + so[2] + so[3];
    }
}

// =============== 256x256 8-phase bf16 MFMA GEMM (R6/R8 schedule — measured best 76.0us) ===============
__device__ __forceinline__ void stage_half(const unsigned short* __restrict__ G,
                                           int grow0, int k0, int lds_byte_base,
                                           int tid, char* ldsp) {
    #pragma unroll
    for (int l = 0; l < 2; ++l) {
        const int flat = l * 512 + tid;            // 16B slot index 0..1023
        const int row = flat >> 3, j = flat & 7;
        const int jsw = j ^ (row & 7);
        const unsigned short* src = G + (size_t)(grow0 + row) * KDIM + k0 + jsw * 8;
        __builtin_amdgcn_global_load_lds(
            (const __attribute__((address_space(1))) void*)src,
            (__attribute__((address_space(3))) void*)(ldsp + lds_byte_base + flat * 16),
            16, 0, 0);
    }
}

#define STAGE_A(buf, half, tt) stage_half(A,  bm + (half) * 128, (tt) * 64, ((buf) * 4 + (half)) * 16384, tid, ldsp)
#define STAGE_B(buf, half, tt) stage_half(Bm, bn + (half) * 128, (tt) * 64, ((buf) * 4 + 2 + (half)) * 16384, tid, ldsp)

#define LDA(mf, buf) do { \
    const int rowh_ = (mf) * 16 + l15; \
    const char* p_ = ldsp + ((buf) * 4 + aregion) * 16384 + rowh_ * 128; \
    const int sw_ = (rowh_ & 7) << 4; \
    af[(mf) & 3][0] = *(const bf16x8*)(p_ + ((l4 << 4) ^ sw_)); \
    af[(mf) & 3][1] = *(const bf16x8*)(p_ + (((4 + l4) << 4) ^ sw_)); \
} while (0)

#define LDB(nf, buf) do { \
    const int rowh_ = (wc & 1) * 64 + (nf) * 16 + l15; \
    const char* p_ = ldsp + ((buf) * 4 + bregion) * 16384 + rowh_ * 128; \
    const int sw_ = (rowh_ & 7) << 4; \
    bf[nf][0] = *(const bf16x8*)(p_ + ((l4 << 4) ^ sw_)); \
    bf[nf][1] = *(const bf16x8*)(p_ + (((4 + l4) << 4) ^ sw_)); \
} while (0)

#define MM(mh, nh) do { \
    __builtin_amdgcn_s_setprio(1); \
    _Pragma("unroll") \
    for (int mi = 0; mi < 4; ++mi) \
        _Pragma("unroll") \
        for (int ni = 0; ni < 2; ++ni) \
            _Pragma("unroll") \
            for (int kk = 0; kk < 2; ++kk) \
                acc[(mh) * 4 + mi][(nh) * 2 + ni] = __builtin_amdgcn_mfma_f32_16x16x32_bf16( \
                    af[mi][kk], bf[(nh) * 2 + ni][kk], acc[(mh) * 4 + mi][(nh) * 2 + ni], 0, 0, 0); \
    __builtin_amdgcn_s_setprio(0); \
} while (0)

#define SBAR() do { \
    __builtin_amdgcn_sched_barrier(0); \
    __builtin_amdgcn_s_barrier(); \
    __builtin_amdgcn_sched_barrier(0); \
} while (0)

__global__ void __launch_bounds__(512, 2) gemm8(
    const unsigned short* __restrict__ A,    // [NB, KDIM] bf16 bits
    const unsigned short* __restrict__ Bm,   // [NPAD, KDIM] bf16 bits
    const float* __restrict__ biasN,
    unsigned short* __restrict__ Co)         // [NB, NPAD] bf16 bits
{
    __shared__ __align__(16) unsigned short lds[65536];   // 128 KiB
    char* ldsp = (char*)lds;
    const int tid = threadIdx.x;
    const int lane = tid & 63, wid = tid >> 6;
    const int wr = wid >> 2, wc = wid & 3;               // 2M x 4N waves
    const int l15 = lane & 15, l4 = lane >> 4;

    const int b = blockIdx.x;
    const int wg = (b & 7) * 32 + (b >> 3);              // bijective XCD swizzle, 256 blocks
    const int bm = (wg >> 2) * 256;
    const int bn = (wg & 3) * 256;

    const int aregion = wr;
    const int bregion = 2 + (wc >> 1);

    f32x4 acc[8][4] = {{}};
    bf16x8 af[4][2], bf[4][2];

    // ---- prologue: tile0 fully + tile1 {A0,B0,B1}; A1(1) staged at P1(t=0)
    STAGE_A(0, 0, 0); STAGE_A(0, 1, 0); STAGE_B(0, 0, 0); STAGE_B(0, 1, 0);
    STAGE_A(1, 0, 1); STAGE_B(1, 0, 1); STAGE_B(1, 1, 1);
    __builtin_amdgcn_sched_barrier(0);
    asm volatile("s_waitcnt vmcnt(6)");
    SBAR();

    for (int t = 0; t < 32; ++t) {
        const int buf = t & 1, nbuf = buf ^ 1;
        // --- P1: read A(mh0)+B(nh0) of t; stage A1(t+1)
        LDA(0, buf); LDA(1, buf); LDA(2, buf); LDA(3, buf);
        LDB(0, buf); LDB(1, buf);
        if (t + 1 < 32) STAGE_A(nbuf, 1, t + 1);
        SBAR();
        MM(0, 0);
        SBAR();
        // --- P2: read B(nh1)
        LDB(2, buf); LDB(3, buf);
        SBAR();
        MM(0, 1);
        SBAR();
        // --- P3: read A(mh1); stage B0(t+2)
        LDA(4, buf); LDA(5, buf); LDA(6, buf); LDA(7, buf);
        if (t + 2 < 32) STAGE_B(buf, 0, t + 2);
        SBAR();
        MM(1, 1);
        SBAR();
        // --- P4: no reads; stage A0(t+2), B1(t+2); counted vmcnt gate
        if (t + 2 < 32) { STAGE_A(buf, 0, t + 2); STAGE_B(buf, 1, t + 2); }
        SBAR();
        MM(1, 0);
        __builtin_amdgcn_sched_barrier(0);
        if (t < 30) { asm volatile("s_waitcnt vmcnt(6)"); }
        else        { asm volatile("s_waitcnt vmcnt(0)"); }
        __builtin_amdgcn_sched_barrier(0);
        __builtin_amdgcn_s_barrier();
        __builtin_amdgcn_sched_barrier(0);
    }

    // ---- epilogue: bias + bf16 store (C frag: col=lane&15, row=(lane>>4)*4+r)
    #pragma unroll
    for (int n = 0; n < 4; ++n) {
        const int col = bn + wc * 64 + n * 16 + l15;
        const float bv = biasN[col];
        #pragma unroll
        for (int m = 0; m < 8; ++m) {
            const int row0 = bm + wr * 128 + m * 16 + l4 * 4;
            #pragma unroll
            for (int r = 0; r < 4; ++r)
                Co[(size_t)(row0 + r) * NPAD + col] = f2bf_bits(acc[m][n][r] + bv);
        }
    }
}

// ---------------- softmax stats (bf16 logits): one wave per batch row ----------------
// No max-reduce: fixed shift exp(v-20). No sum(p)-reduce (==1). One cross-lane pass.
__global__ void stats_kernel(const unsigned short* __restrict__ Co,
                             const float* __restrict__ partials,
                             float* __restrict__ out) {
    const int lane = threadIdx.x & 63;
    const int wid = threadIdx.x >> 6;
    const int b = blockIdx.x * 4 + wid;
    const unsigned short* row = Co + (size_t)b * NPAD;
    float* pm = out;
    float* aleat_out = out + PM_SIZE + 2;
    float* epi_out   = out + PM_SIZE + 2 + NB;

    const bool has2 = lane < (NCLS - 64);
    float p1s[NP], p2s[NP];
    float pm1 = 0.f, pm2 = 0.f, pb1 = 0.f, pb2 = 0.f, sqacc = 0.f;

    for (int n = 0; n < NP; ++n) {
        const float v1 = bfu(row[n * NCLS + lane]);
        const float v2 = has2 ? bfu(row[n * NCLS + 64 + lane]) : 0.f;
        const float e1 = __expf(v1 - 20.f);
        const float e2 = has2 ? __expf(v2 - 20.f) : 0.f;
        float s = e1 + e2;
        for (int off = 32; off; off >>= 1) s += __shfl_xor(s, off);
        const float rs = 1.0f / s;
        const float p1 = e1 * rs, p2 = e2 * rs;
        sqacc += p1 * p1 + p2 * p2;
        pm1 += v1; pm2 += v2;
        pb1 += p1; pb2 += p2;
        p1s[n] = p1; p2s[n] = p2;
    }
    const float inv_n = 1.0f / NP;
    pb1 *= inv_n; pb2 *= inv_n;
    pm[(size_t)b * NCLS + lane] = pm1 * inv_n;
    if (has2) pm[(size_t)b * NCLS + 64 + lane] = pm2 * inv_n;
    float epi = 0.f;
    #pragma unroll
    for (int n = 0; n < NP; ++n) {
        const float d1 = p1s[n] - pb1;
        const float d2 = p2s[n] - pb2;
        epi += d1 * d1 + d2 * d2;
    }
    for (int off = 32; off; off >>= 1) {
        epi   += __shfl_xor(epi, off);
        sqacc += __shfl_xor(sqacc, off);
    }
    if (lane == 0) {
        aleat_out[b] = 1.0f - sqacc * inv_n;
        epi_out[b]   = epi * inv_n;
    }
    // block 0, wave 0: reduce prior/posterior partials -> scalars
    if (blockIdx.x == 0 && wid == 0) {
        float a = 0.f, c = 0.f;
        for (int i = lane; i < NBLK_PW + 1; i += 64) {
            a += partials[2 * i];
            c += partials[2 * i + 1];
        }
        for (int off = 32; off; off >>= 1) {
            a += __shfl_xor(a, off);
            c += __shfl_xor(c, off);
        }
        if (lane == 0) {
            out[PM_SIZE]     = a * (1.0f / NP);
            out[PM_SIZE + 1] = c * (1.0f / NP);
        }
    }
}

extern "C" void kernel_launch(void* const* d_in, const int* in_sizes, int n_in,
                              void* d_out, int out_size, void* d_ws, size_t ws_size,
                              hipStream_t stream) {
    const float* x     = (const float*)d_in[0];
    const float* wmu   = (const float*)d_in[1];
    const float* wrho  = (const float*)d_in[2];
    const float* bmu   = (const float*)d_in[3];
    const float* brho  = (const float*)d_in[4];
    const float* eps_w = (const float*)d_in[5];
    const float* eps_b = (const float*)d_in[6];
    float* out = (float*)d_out;

    char* ws = (char*)d_ws;
    const size_t OFF_XB    = 0;                          // 16384*2048*2 = 67108864
    const size_t OFF_WB    = 67108864;                   // 1024*2048*2  =  4194304
    const size_t OFF_COUT  = OFF_WB + 4194304;           // 16384*1024*2 = 33554432
    const size_t OFF_BIASN = OFF_COUT + 33554432;        // 4096
    const size_t OFF_PART  = OFF_BIASN + 4096;           // 809*2*4

    unsigned short* xb   = (unsigned short*)(ws + OFF_XB);
    unsigned short* wB   = (unsigned short*)(ws + OFF_WB);
    unsigned short* Co   = (unsigned short*)(ws + OFF_COUT);
    float* biasN    = (float*)(ws + OFF_BIASN);
    float* partials = (float*)(ws + OFF_PART);

    prep_all<<<NBLK_CVT + NBLK_PW + 1, 256, 0, stream>>>(x, xb, wmu, wrho, eps_w,
                                                         bmu, brho, eps_b,
                                                         wB, biasN, partials);
    gemm8<<<256, 512, 0, stream>>>(xb, wB, biasN, Co);
    stats_kernel<<<NB / 4, 256, 0, stream>>>(Co, partials, out);
}